// Round 2
// baseline (609.055 us; speedup 1.0000x reference)
//
#include <hip/hip_runtime.h>
#include <hip/hip_bf16.h>

// GraphResBlock on MI355X — round 7.
// GEMMs: 64row x 256col tiles, BK=32, dbuf LDS, 4 waves (each 64x64), MFMA bf16.
// Final GEMM reads pre-converted bf16 xb (MODE 2) if ws_size permits, else streams fp32 (MODE 3).
// GAT agg rework: compulsory-miss elimination.
//   - MODE 1 writes h in XCD-blocked layout hb[cb][node][32ch] (64B per node per block).
//   - alpha_k (wave/node) precomputes packed (sid, alpha) per edge + 1/sum per node.
//   - gat_pass_k: grid = nodegroups*8, blockIdx%8 = channel-block -> pinned to one XCD
//     (round-robin dispatch heuristic). Each XCD touches only 2.56MB of h (fits L2).
//     Edge stream (sid,alpha) loaded non-temporally (no reuse within an XCD).
// CSR: parallel 3-stage scan.

typedef __bf16 bf16x8 __attribute__((ext_vector_type(8)));
typedef float floatx4 __attribute__((ext_vector_type(4)));

__device__ __forceinline__ __hip_bfloat16 f2b(float f) { return __float2bfloat16(f); }
__device__ __forceinline__ float bits2f(unsigned u) { return __uint_as_float(u << 16); }

__device__ __forceinline__ bf16x8 cvt8(const float* p) {
  float4 a = *(const float4*)p, b = *(const float4*)(p + 4);
  bf16x8 r;
  r[0] = (__bf16)a.x; r[1] = (__bf16)a.y; r[2] = (__bf16)a.z; r[3] = (__bf16)a.w;
  r[4] = (__bf16)b.x; r[5] = (__bf16)b.y; r[6] = (__bf16)b.z; r[7] = (__bf16)b.w;
  return r;
}

// ---------------- weight fp32 -> bf16 pack ----------------
__global__ __launch_bounds__(256) void conv_w_k(
    const float* __restrict__ s0, const float* __restrict__ s1,
    const float* __restrict__ s2, const float* __restrict__ s3,
    const float* __restrict__ s4, __hip_bfloat16* __restrict__ d) {
  int i = (blockIdx.x * 256 + threadIdx.x) * 4;
  if (i >= 458752) return;
  const float* s; int off;
  if      (i < 65536)  { s = s0; off = 0; }
  else if (i < 131072) { s = s1; off = 65536; }
  else if (i < 196608) { s = s2; off = 131072; }
  else if (i < 327680) { s = s3; off = 196608; }
  else                 { s = s4; off = 327680; }
  float4 v = *(const float4*)(s + (i - off));
  union { ushort4 u; __hip_bfloat16 h[4]; } st;
  st.h[0] = f2b(v.x); st.h[1] = f2b(v.y); st.h[2] = f2b(v.z); st.h[3] = f2b(v.w);
  *(ushort4*)(d + i) = st.u;
}

// ---------------- pre GroupNorm(8) + ELU (+ optional raw x -> bf16) ----------------
__global__ __launch_bounds__(256) void gn_elu_k(
    const float* __restrict__ x, const float* __restrict__ w, const float* __restrict__ b,
    __hip_bfloat16* __restrict__ o, __hip_bfloat16* __restrict__ xb, int ng) {
  int g = blockIdx.x * 256 + threadIdx.x;
  if (g >= ng) return;
  int gi = g & 31;
  size_t basei = (size_t)g * 8;
  float4 u0 = *(const float4*)(x + basei), u1 = *(const float4*)(x + basei + 4);
  float f[8] = {u0.x, u0.y, u0.z, u0.w, u1.x, u1.y, u1.z, u1.w};
  if (xb) {
    union { uint4 u; __hip_bfloat16 h[8]; } xs;
#pragma unroll
    for (int i = 0; i < 8; i++) xs.h[i] = f2b(f[i]);
    *(uint4*)(xb + basei) = xs.u;
  }
  float mu = 0.f;
#pragma unroll
  for (int i = 0; i < 8; i++) mu += f[i];
  mu *= 0.125f;
  float var = 0.f;
#pragma unroll
  for (int i = 0; i < 8; i++) { float d = f[i] - mu; var += d * d; }
  float inv = rsqrtf(var * 0.125f + 1e-5f);
  union { uint4 u; __hip_bfloat16 h[8]; } st;
#pragma unroll
  for (int i = 0; i < 8; i++) {
    float vv = (f[i] - mu) * inv * w[gi * 8 + i] + b[gi * 8 + i];
    vv = (vv > 0.f) ? vv : (__expf(vv) - 1.f);
    st.h[i] = f2b(vv);
  }
  *(uint4*)(o + basei) = st.u;
}

// ---------------- MFMA GEMM: 64 x 256 tile, BK=32, dbuf LDS, 256 threads ----------------
// MODE 0: outB = ELU(GN8(A@W^T + bias)) bf16, Nc=256, standard [row][256] layout
// MODE 1: outB = A@W^T bf16 in BLOCKED layout hb[col>>5][row][col&31]; asrc/adst row dots
// MODE 2: outF = A@W^T + A2@W2^T + bias + bias2 fp32, Nc=512 (A2 bf16 staged)
// MODE 3: like 2 but second half streams Af32 (fp32 x) per-wave
template <int MODE>
__global__ __launch_bounds__(256, 3) void gemm_t(
    const __hip_bfloat16* __restrict__ A, const __hip_bfloat16* __restrict__ A2,
    const float* __restrict__ Af32,
    const __hip_bfloat16* __restrict__ W, const __hip_bfloat16* __restrict__ W2,
    const float* __restrict__ bias, const float* __restrict__ bias2,
    const float* __restrict__ gnw, const float* __restrict__ gnb,
    const float* __restrict__ avs, const float* __restrict__ avd,
    __hip_bfloat16* __restrict__ outB, float* __restrict__ outF,
    float* __restrict__ asrc, float* __restrict__ adst, int Nc, int Mreal) {
  const int tid = threadIdx.x;
  const int wn = tid >> 6, lane = tid & 63;
  const int l16 = lane & 15, quad = lane >> 4;
  const int rows0 = blockIdx.y * 64;
  const int col0 = blockIdx.x * 256;
  const int srow = tid >> 2, skc = (tid & 3) * 8;
  __shared__ __align__(16) __hip_bfloat16 sA[2][64 * 32];
  __shared__ __align__(16) __hip_bfloat16 sB[2][256 * 32];
  __shared__ float sRed[2][64][4];
  const int loA = tid * 8;  // = srow*32 + skc

  floatx4 acc[4][4];
#pragma unroll
  for (int a = 0; a < 4; ++a)
#pragma unroll
    for (int b = 0; b < 4; ++b) acc[a][b] = (floatx4){0.f, 0.f, 0.f, 0.f};

  const int NK = (MODE >= 2) ? 16 : 8;
  uint4 pa, pb[4];
  pa = *(const uint4*)(A + (size_t)(rows0 + srow) * 256 + skc);
#pragma unroll
  for (int h = 0; h < 4; ++h)
    pb[h] = *(const uint4*)(W + (size_t)(col0 + srow + h * 64) * 256 + skc);
  *(uint4*)(&sA[0][loA]) = pa;
#pragma unroll
  for (int h = 0; h < 4; ++h) *(uint4*)(&sB[0][loA + h * 2048]) = pb[h];
  __syncthreads();

#pragma unroll
  for (int kt = 0; kt < NK; ++kt) {
    const int cur = kt & 1, nxt = cur ^ 1;
    const int ktn = kt + 1;
    const bool nsec = (MODE >= 2) && (ktn >= 8);
    const bool nstageA = (ktn < NK) && !(MODE == 3 && nsec);
    if (ktn < NK) {
      const int kkn = (ktn & 7) * 32;
      const __hip_bfloat16* Wb = nsec ? W2 : W;
      if (nstageA) {
        const __hip_bfloat16* Ab = (MODE == 2 && nsec) ? A2 : A;
        pa = *(const uint4*)(Ab + (size_t)(rows0 + srow) * 256 + kkn + skc);
      }
#pragma unroll
      for (int h = 0; h < 4; ++h)
        pb[h] = *(const uint4*)(Wb + (size_t)(col0 + srow + h * 64) * 256 + kkn + skc);
    }
    bf16x8 af[4], bfr[4];
    if (MODE == 3 && kt >= 8) {
      const int kk = (kt & 7) * 32;
#pragma unroll
      for (int ri = 0; ri < 4; ++ri) {
        int row = min(rows0 + ri * 16 + l16, Mreal - 1);
        af[ri] = cvt8(Af32 + (size_t)row * 256 + kk + quad * 8);
      }
    } else {
#pragma unroll
      for (int ri = 0; ri < 4; ++ri)
        af[ri] = *(const bf16x8*)(&sA[cur][(ri * 16 + l16) * 32 + quad * 8]);
    }
#pragma unroll
    for (int ci = 0; ci < 4; ++ci)
      bfr[ci] = *(const bf16x8*)(&sB[cur][(wn * 64 + ci * 16 + l16) * 32 + quad * 8]);
#pragma unroll
    for (int ri = 0; ri < 4; ++ri)
#pragma unroll
      for (int ci = 0; ci < 4; ++ci)
        acc[ri][ci] = __builtin_amdgcn_mfma_f32_16x16x32_bf16(af[ri], bfr[ci], acc[ri][ci], 0, 0, 0);
    if (ktn < NK) {
      if (nstageA) *(uint4*)(&sA[nxt][loA]) = pa;
#pragma unroll
      for (int h = 0; h < 4; ++h) *(uint4*)(&sB[nxt][loA + h * 2048]) = pb[h];
    }
    __syncthreads();
  }

  // C/D layout: col = col0 + wn*64 + ci*16 + l16; row = rows0 + ri*16 + quad*4 + i
  if (MODE == 0) {
#pragma unroll
    for (int ri = 0; ri < 4; ++ri)
#pragma unroll
      for (int ci = 0; ci < 4; ++ci) {
        int col = col0 + wn * 64 + ci * 16 + l16;
        float bs = bias[col], gw = gnw[col], gb = gnb[col];
#pragma unroll
        for (int i = 0; i < 4; ++i) {
          float v = acc[ri][ci][i] + bs;
          float s = v;
          s += __shfl_xor(s, 1, 64); s += __shfl_xor(s, 2, 64); s += __shfl_xor(s, 4, 64);
          float mu = s * 0.125f, d = v - mu;
          float q = d * d;
          q += __shfl_xor(q, 1, 64); q += __shfl_xor(q, 2, 64); q += __shfl_xor(q, 4, 64);
          float r = d * rsqrtf(q * 0.125f + 1e-5f) * gw + gb;
          r = (r > 0.f) ? r : (__expf(r) - 1.f);
          outB[(size_t)(rows0 + ri * 16 + quad * 4 + i) * 256 + col] = f2b(r);
        }
      }
  } else if (MODE == 1) {
    const int NPl = (Mreal + 127) & ~127;
#pragma unroll
    for (int ri = 0; ri < 4; ++ri) {
      float ps[4] = {0.f, 0.f, 0.f, 0.f}, pd[4] = {0.f, 0.f, 0.f, 0.f};
#pragma unroll
      for (int ci = 0; ci < 4; ++ci) {
        int col = col0 + wn * 64 + ci * 16 + l16;
        int cbk = col >> 5, chin = col & 31;
        float wsv = avs[col], wdv = avd[col];
#pragma unroll
        for (int i = 0; i < 4; ++i) {
          float v = acc[ri][ci][i];
          int row = rows0 + ri * 16 + quad * 4 + i;
          outB[(size_t)cbk * NPl * 32 + (size_t)row * 32 + chin] = f2b(v);
          ps[i] += v * wsv; pd[i] += v * wdv;
        }
      }
#pragma unroll
      for (int i = 0; i < 4; ++i) {
        ps[i] += __shfl_xor(ps[i], 1, 64); ps[i] += __shfl_xor(ps[i], 2, 64);
        ps[i] += __shfl_xor(ps[i], 4, 64); ps[i] += __shfl_xor(ps[i], 8, 64);
        pd[i] += __shfl_xor(pd[i], 1, 64); pd[i] += __shfl_xor(pd[i], 2, 64);
        pd[i] += __shfl_xor(pd[i], 4, 64); pd[i] += __shfl_xor(pd[i], 8, 64);
        if (l16 == 0) {
          int r = ri * 16 + quad * 4 + i;
          sRed[0][r][wn] = ps[i];
          sRed[1][r][wn] = pd[i];
        }
      }
    }
    __syncthreads();
    if (tid < 128) {
      int arr = tid >> 6, r = tid & 63;
      float v = sRed[arr][r][0] + sRed[arr][r][1] + sRed[arr][r][2] + sRed[arr][r][3];
      (arr ? adst : asrc)[rows0 + r] = v;
    }
  } else {
#pragma unroll
    for (int ri = 0; ri < 4; ++ri)
#pragma unroll
      for (int ci = 0; ci < 4; ++ci) {
        int col = col0 + wn * 64 + ci * 16 + l16;
        float bs = bias[col] + bias2[col];
#pragma unroll
        for (int i = 0; i < 4; ++i) {
          int row = rows0 + ri * 16 + quad * 4 + i;
          if (row < Mreal) outF[(size_t)row * Nc + col] = acc[ri][ci][i] + bs;
        }
      }
  }
}

// ---------------- CSR build ----------------
__global__ void zero_k(int* p, int n) {
  int i = blockIdx.x * blockDim.x + threadIdx.x;
  if (i < n) p[i] = 0;
}

__global__ void count_deg_k(const int* __restrict__ ei, int E, int NN, int* __restrict__ counts) {
  int e = blockIdx.x * blockDim.x + threadIdx.x;
  if (e >= E + NN) return;
  int d = (e < E) ? ei[E + e] : (e - E);
  if ((unsigned)d >= (unsigned)NN) d = 0;
  atomicAdd(&counts[d], 1);
}

__global__ __launch_bounds__(1024) void scan_blk_k(const int* __restrict__ counts,
                                                   int* __restrict__ indptr,
                                                   int* __restrict__ bsums, int NN) {
  __shared__ int wsum[16];
  int t = threadIdx.x, idx = blockIdx.x * 1024 + t;
  int lane = t & 63, wid = t >> 6;
  int v = (idx < NN) ? counts[idx] : 0;
  int s = v;
#pragma unroll
  for (int off = 1; off < 64; off <<= 1) {
    int u = __shfl_up(s, off, 64);
    if (lane >= off) s += u;
  }
  if (lane == 63) wsum[wid] = s;
  __syncthreads();
  if (t == 0) {
    int run = 0;
#pragma unroll
    for (int i = 0; i < 16; i++) { int u = wsum[i]; wsum[i] = run; run += u; }
    bsums[blockIdx.x] = run;
  }
  __syncthreads();
  if (idx < NN) indptr[idx] = s - v + wsum[wid];
}

__global__ void scan_top_k(int* bsums, int nb) {
  if (threadIdx.x == 0) {
    int run = 0;
    for (int i = 0; i < nb; i++) { int t = bsums[i]; bsums[i] = run; run += t; }
  }
}

__global__ __launch_bounds__(1024) void scan_add_k(int* __restrict__ indptr, int* __restrict__ fill,
                                                   const int* __restrict__ bsums, int NN, int ET) {
  int idx = blockIdx.x * 1024 + threadIdx.x;
  if (idx < NN) {
    int v = indptr[idx] + bsums[blockIdx.x];
    indptr[idx] = v; fill[idx] = v;
  }
  if (idx == 0) indptr[NN] = ET;
}

__global__ void fill_csr_k(const int* __restrict__ ei, int E, int NN,
                           int* __restrict__ fill, int* __restrict__ csr, int ET) {
  int e = blockIdx.x * blockDim.x + threadIdx.x;
  if (e >= E + NN) return;
  int s, d;
  if (e < E) { s = ei[e]; d = ei[E + e]; } else { s = e - E; d = e - E; }
  if ((unsigned)d >= (unsigned)NN) d = 0;
  if ((unsigned)s >= (unsigned)NN) s = 0;
  int slot = atomicAdd(&fill[d], 1);
  if ((unsigned)slot < (unsigned)ET) csr[slot] = s;
}

// ---------------- alpha precompute: wave/node, packed (sid, alpha) + 1/sum ----------------
__global__ __launch_bounds__(256) void alpha_k(
    const float* __restrict__ asrc, const float* __restrict__ adst,
    const int* __restrict__ indptr, const int* __restrict__ csr,
    unsigned long long* __restrict__ ew, float* __restrict__ lwinv, int NN, int ET) {
  int n = blockIdx.x * 4 + (threadIdx.x >> 6);
  if (n >= NN) return;
  int lane = threadIdx.x & 63;
  int beg = indptr[n], end = indptr[n + 1];
  beg = max(0, min(beg, ET));
  end = max(beg, min(end, ET));
  int deg = end - beg;
  float adn = adst[n];
  float lw = 0.f;
  for (int c0 = 0; c0 < deg; c0 += 64) {
    int j = c0 + lane;
    if (j < deg) {
      int sid = csr[beg + j];
      if ((unsigned)sid >= (unsigned)NN) sid = 0;
      float e = asrc[sid] + adn;
      e = (e > 0.f) ? e : 0.2f * e;                  // leaky_relu 0.2
      e = fminf(fmaxf(e, -60.f), 60.f);              // softmax shift-invariant; clamp
      float w = __expf(e);
      ew[beg + j] = (unsigned)sid | ((unsigned long long)__float_as_uint(w) << 32);
      lw += w;
    }
  }
#pragma unroll
  for (int m = 32; m >= 1; m >>= 1) lw += __shfl_xor(lw, m, 64);
  if (lane == 0) lwinv[n] = 1.f / (lw + 1e-16f);
}

// ---------------- GAT agg pass: XCD-pinned channel block ----------------
// grid.x = nodegroups*8; blockIdx%8 = channel block (-> one XCD via round-robin dispatch).
// Each XCD touches only hb[cb] = 40000*64B = 2.56MB (fits 4MB L2) -> compulsory misses /8.
// Quarter-wave per edge: 16 lanes x 4B = one 64B segment. Edge stream (sid,alpha) via nt load.
__global__ __launch_bounds__(256) void gat_pass_k(
    const __hip_bfloat16* __restrict__ hb, const unsigned long long* __restrict__ ew,
    const float* __restrict__ lwinv, const int* __restrict__ indptr,
    const float* __restrict__ gbias, const float* __restrict__ gnw,
    const float* __restrict__ gnb, __hip_bfloat16* __restrict__ outp,
    int NN, int NP, int ET) {
  int bid = blockIdx.x;
  int cbk = bid & 7;
  int n = (bid >> 3) * 4 + (threadIdx.x >> 6);
  if (n >= NN) return;
  int lane = threadIdx.x & 63;
  int qw = lane >> 4, l16 = lane & 15;
  const __hip_bfloat16* hc = hb + (size_t)cbk * NP * 32;
  int beg = indptr[n], end = indptr[n + 1];
  beg = max(0, min(beg, ET));
  end = max(beg, min(end, ET));
  int deg = end - beg;
  float a0 = 0.f, a1 = 0.f;

  for (int c0 = 0; c0 < deg; c0 += 64) {
    int j = c0 + lane;
    int sid = 0; float w = 0.f;
    if (j < deg) {
      unsigned long long pv = __builtin_nontemporal_load(ew + beg + j);
      sid = (int)(unsigned)pv;
      w = __uint_as_float((unsigned)(pv >> 32));
    }
    int cnt = min(64, deg - c0);
    for (int t = 0; t < cnt; t += 16) {
      // quarter-wave per edge: quarter q handles edges t+q, t+4+q, t+8+q, t+12+q
      int i0 = t + qw, i1 = t + 4 + qw, i2 = t + 8 + qw, i3 = t + 12 + qw;
      int s0 = __shfl(sid, i0, 64), s1 = __shfl(sid, i1, 64),
          s2 = __shfl(sid, i2, 64), s3 = __shfl(sid, i3, 64);
      float w0 = __shfl(w, i0, 64), w1 = __shfl(w, i1, 64),
            w2 = __shfl(w, i2, 64), w3 = __shfl(w, i3, 64);
      unsigned u0 = *(const unsigned*)(hc + (size_t)s0 * 32 + l16 * 2);
      unsigned u1 = *(const unsigned*)(hc + (size_t)s1 * 32 + l16 * 2);
      unsigned u2 = *(const unsigned*)(hc + (size_t)s2 * 32 + l16 * 2);
      unsigned u3 = *(const unsigned*)(hc + (size_t)s3 * 32 + l16 * 2);
      a0 += w0 * bits2f(u0 & 0xffffu); a1 += w0 * bits2f(u0 >> 16);
      a0 += w1 * bits2f(u1 & 0xffffu); a1 += w1 * bits2f(u1 >> 16);
      a0 += w2 * bits2f(u2 & 0xffffu); a1 += w2 * bits2f(u2 >> 16);
      a0 += w3 * bits2f(u3 & 0xffffu); a1 += w3 * bits2f(u3 >> 16);
    }
  }
  // reduce across quarters: lanes 0..15 end with full sums of channel pair l16*2
  a0 += __shfl_xor(a0, 16, 64); a0 += __shfl_xor(a0, 32, 64);
  a1 += __shfl_xor(a1, 16, 64); a1 += __shfl_xor(a1, 32, 64);
  if (qw == 0) {
    float inv = lwinv[n];
    int ch = cbk * 32 + l16 * 2;
    float v0 = a0 * inv + gbias[ch], v1 = a1 * inv + gbias[ch + 1];
    // GN group of 8 channels = 4 lanes
    float s = v0 + v1;
    s += __shfl_xor(s, 1, 64); s += __shfl_xor(s, 2, 64);
    float mu = s * 0.125f;
    float d0 = v0 - mu, d1 = v1 - mu;
    float q = d0 * d0 + d1 * d1;
    q += __shfl_xor(q, 1, 64); q += __shfl_xor(q, 2, 64);
    float rs = rsqrtf(q * 0.125f + 1e-5f);
    float r0 = d0 * rs * gnw[ch] + gnb[ch];
    r0 = (r0 > 0.f) ? r0 : (__expf(r0) - 1.f);
    float r1 = d1 * rs * gnw[ch + 1] + gnb[ch + 1];
    r1 = (r1 > 0.f) ? r1 : (__expf(r1) - 1.f);
    union { unsigned u; __hip_bfloat16 h[2]; } st;
    st.h[0] = f2b(r0); st.h[1] = f2b(r1);
    *(unsigned*)(outp + (size_t)n * 256 + ch) = st.u;
  }
}

// ---------------- launch ----------------
extern "C" void kernel_launch(void* const* d_in, const int* in_sizes, int n_in,
                              void* d_out, int out_size, void* d_ws, size_t ws_size,
                              hipStream_t stream) {
  const float* x      = (const float*)d_in[0];
  const int*   ei     = (const int*)d_in[1];
  const float* pre_w  = (const float*)d_in[2];
  const float* pre_b  = (const float*)d_in[3];
  const float* lin1_b = (const float*)d_in[5];
  const float* n1_w   = (const float*)d_in[6];
  const float* n1_b   = (const float*)d_in[7];
  const float* g1_as  = (const float*)d_in[9];
  const float* g1_ad  = (const float*)d_in[10];
  const float* g1_b   = (const float*)d_in[11];
  const float* n2_w   = (const float*)d_in[12];
  const float* n2_b   = (const float*)d_in[13];
  const float* g2_as  = (const float*)d_in[15];
  const float* g2_ad  = (const float*)d_in[16];
  const float* g2_b   = (const float*)d_in[17];
  const float* n3_w   = (const float*)d_in[18];
  const float* n3_b   = (const float*)d_in[19];
  const float* lin2_b = (const float*)d_in[21];
  const float* skip_b = (const float*)d_in[23];
  float* out = (float*)d_out;

  const int C_IN  = in_sizes[2];          // 256
  const int NN    = in_sizes[0] / C_IN;   // 40000
  const int E     = in_sizes[1] / 2;      // 640000
  const int ET    = E + NN;
  const int C_OUT = in_sizes[21];         // 512
  const int NP    = (NN + 127) & ~127;    // 40064

  __hip_bfloat16* D0 = (__hip_bfloat16*)d_out;        // bf16 scratch in d_out
  __hip_bfloat16* D1 = D0 + (size_t)NP * 256;

  char* basep = (char*)d_ws;
  size_t o = 0;
  auto alloc = [&](size_t bytes) { size_t r = o; o += (bytes + 255) & ~(size_t)255; return r; };
  __hip_bfloat16* Y      = (__hip_bfloat16*)(basep + alloc((size_t)NP * 256 * 2));
  __hip_bfloat16* Wcat   = (__hip_bfloat16*)(basep + alloc((size_t)458752 * 2));
  float*          asrc   = (float*)(basep + alloc((size_t)NP * 4));
  float*          adst   = (float*)(basep + alloc((size_t)NP * 4));
  int*            indptr = (int*)(basep + alloc((size_t)(NN + 1) * 4));
  int*            counts = (int*)(basep + alloc((size_t)NN * 4));
  int*            fill   = (int*)(basep + alloc((size_t)NN * 4));
  int*            bsums  = (int*)(basep + alloc(256));
  int*            csr    = (int*)(basep + alloc((size_t)ET * 4));
  unsigned long long* ew = (unsigned long long*)(basep + alloc((size_t)ET * 8));
  float*          lwinv  = (float*)(basep + alloc((size_t)NN * 4));
  size_t base_need = o;
  size_t xb_need = ((size_t)NP * 256 * 2 + 255) & ~(size_t)255;
  const bool use_xb = (ws_size >= base_need + xb_need);
  __hip_bfloat16* xb = use_xb ? (__hip_bfloat16*)(basep + alloc(xb_need)) : nullptr;

  __hip_bfloat16* Wlin1 = Wcat;
  __hip_bfloat16* Wg1   = Wcat + 65536;
  __hip_bfloat16* Wg2   = Wcat + 131072;
  __hip_bfloat16* Wlin2 = Wcat + 196608;
  __hip_bfloat16* Wskip = Wcat + 327680;

  dim3 blk(256);
  const int nb = (NN + 1023) / 1024;      // 40
  const int ngrp = (NN + 3) / 4;          // 10000

  conv_w_k<<<(458752 / 4 + 255) / 256, blk, 0, stream>>>(
      (const float*)d_in[4], (const float*)d_in[8], (const float*)d_in[14],
      (const float*)d_in[20], (const float*)d_in[22], Wcat);
  zero_k<<<(NN + 255) / 256, blk, 0, stream>>>(counts, NN);
  count_deg_k<<<(ET + 255) / 256, blk, 0, stream>>>(ei, E, NN, counts);
  scan_blk_k<<<nb, 1024, 0, stream>>>(counts, indptr, bsums, NN);
  scan_top_k<<<1, 64, 0, stream>>>(bsums, nb);
  scan_add_k<<<nb, 1024, 0, stream>>>(indptr, fill, bsums, NN, ET);
  fill_csr_k<<<(ET + 255) / 256, blk, 0, stream>>>(ei, E, NN, fill, csr, ET);

  gn_elu_k<<<(NN * 32 + 255) / 256, blk, 0, stream>>>(x, pre_w, pre_b, D0, xb, NN * 32);
  // lin1 + GN1 + ELU
  gemm_t<0><<<dim3(1, NP / 64), blk, 0, stream>>>(D0, nullptr, nullptr, Wlin1, nullptr,
      lin1_b, nullptr, n1_w, n1_b, nullptr, nullptr, Y, nullptr, nullptr, nullptr, 256, NN);
  // GAT1: h (blocked) + alpha dots
  gemm_t<1><<<dim3(1, NP / 64), blk, 0, stream>>>(Y, nullptr, nullptr, Wg1, nullptr,
      nullptr, nullptr, nullptr, nullptr, g1_as, g1_ad, D0, nullptr, asrc, adst, 256, NN);
  alpha_k<<<ngrp, blk, 0, stream>>>(asrc, adst, indptr, csr, ew, lwinv, NN, ET);
  gat_pass_k<<<ngrp * 8, blk, 0, stream>>>(D0, ew, lwinv, indptr, g1_b, n2_w, n2_b, D1, NN, NP, ET);
  // GAT2
  gemm_t<1><<<dim3(1, NP / 64), blk, 0, stream>>>(D1, nullptr, nullptr, Wg2, nullptr,
      nullptr, nullptr, nullptr, nullptr, g2_as, g2_ad, D0, nullptr, asrc, adst, 256, NN);
  alpha_k<<<ngrp, blk, 0, stream>>>(asrc, adst, indptr, csr, ew, lwinv, NN, ET);
  gat_pass_k<<<ngrp * 8, blk, 0, stream>>>(D0, ew, lwinv, indptr, g2_b, n3_w, n3_b, Y, NN, NP, ET);
  // lin2 + skip fused -> out (K=512)
  if (use_xb) {
    gemm_t<2><<<dim3(C_OUT / 256, NP / 64), blk, 0, stream>>>(Y, xb, nullptr, Wlin2, Wskip,
        lin2_b, skip_b, nullptr, nullptr, nullptr, nullptr, nullptr, out, nullptr, nullptr, C_OUT, NN);
  } else {
    gemm_t<3><<<dim3(C_OUT / 256, NP / 64), blk, 0, stream>>>(Y, nullptr, x, Wlin2, Wskip,
        lin2_b, skip_b, nullptr, nullptr, nullptr, nullptr, nullptr, out, nullptr, nullptr, C_OUT, NN);
  }
}

// Round 3
// 428.967 us; speedup vs baseline: 1.4198x; 1.4198x over previous
//
#include <hip/hip_runtime.h>
#include <hip/hip_bf16.h>

// GraphResBlock on MI355X — round 8.
// GEMMs: 64row x 256col tiles, BK=32, dbuf LDS, 4 waves (each 64x64), MFMA bf16.
// Final GEMM reads pre-converted bf16 xb (MODE 2) if ws_size permits, else streams fp32 (MODE 3).
// GAT agg: B=1 single pass per edge (round-2's 8x channel split reverted: traffic win was
//   real but 8x per-edge overhead cost 3x). Overhead attack instead:
//   - (sid,w) staged per 64-edge chunk in per-wave LDS (ds_write_b64/ds_read_b64 broadcast),
//     zero main-loop shuffles.
//   - float2 accumulators (v_pk_fma_f32-eligible).
//   - 4-deep independent 16B gathers, half-wave per edge, inline clamped no-max softmax,
//     lane-local GN epilogue.
// CSR: parallel 3-stage scan.

typedef __bf16 bf16x8 __attribute__((ext_vector_type(8)));
typedef float floatx4 __attribute__((ext_vector_type(4)));
typedef float floatx2 __attribute__((ext_vector_type(2)));

__device__ __forceinline__ __hip_bfloat16 f2b(float f) { return __float2bfloat16(f); }
__device__ __forceinline__ float bits2f(unsigned u) { return __uint_as_float(u << 16); }

__device__ __forceinline__ bf16x8 cvt8(const float* p) {
  float4 a = *(const float4*)p, b = *(const float4*)(p + 4);
  bf16x8 r;
  r[0] = (__bf16)a.x; r[1] = (__bf16)a.y; r[2] = (__bf16)a.z; r[3] = (__bf16)a.w;
  r[4] = (__bf16)b.x; r[5] = (__bf16)b.y; r[6] = (__bf16)b.z; r[7] = (__bf16)b.w;
  return r;
}

// ---------------- weight fp32 -> bf16 pack ----------------
__global__ __launch_bounds__(256) void conv_w_k(
    const float* __restrict__ s0, const float* __restrict__ s1,
    const float* __restrict__ s2, const float* __restrict__ s3,
    const float* __restrict__ s4, __hip_bfloat16* __restrict__ d) {
  int i = (blockIdx.x * 256 + threadIdx.x) * 4;
  if (i >= 458752) return;
  const float* s; int off;
  if      (i < 65536)  { s = s0; off = 0; }
  else if (i < 131072) { s = s1; off = 65536; }
  else if (i < 196608) { s = s2; off = 131072; }
  else if (i < 327680) { s = s3; off = 196608; }
  else                 { s = s4; off = 327680; }
  float4 v = *(const float4*)(s + (i - off));
  union { ushort4 u; __hip_bfloat16 h[4]; } st;
  st.h[0] = f2b(v.x); st.h[1] = f2b(v.y); st.h[2] = f2b(v.z); st.h[3] = f2b(v.w);
  *(ushort4*)(d + i) = st.u;
}

// ---------------- pre GroupNorm(8) + ELU (+ optional raw x -> bf16) ----------------
__global__ __launch_bounds__(256) void gn_elu_k(
    const float* __restrict__ x, const float* __restrict__ w, const float* __restrict__ b,
    __hip_bfloat16* __restrict__ o, __hip_bfloat16* __restrict__ xb, int ng) {
  int g = blockIdx.x * 256 + threadIdx.x;
  if (g >= ng) return;
  int gi = g & 31;
  size_t basei = (size_t)g * 8;
  float4 u0 = *(const float4*)(x + basei), u1 = *(const float4*)(x + basei + 4);
  float f[8] = {u0.x, u0.y, u0.z, u0.w, u1.x, u1.y, u1.z, u1.w};
  if (xb) {
    union { uint4 u; __hip_bfloat16 h[8]; } xs;
#pragma unroll
    for (int i = 0; i < 8; i++) xs.h[i] = f2b(f[i]);
    *(uint4*)(xb + basei) = xs.u;
  }
  float mu = 0.f;
#pragma unroll
  for (int i = 0; i < 8; i++) mu += f[i];
  mu *= 0.125f;
  float var = 0.f;
#pragma unroll
  for (int i = 0; i < 8; i++) { float d = f[i] - mu; var += d * d; }
  float inv = rsqrtf(var * 0.125f + 1e-5f);
  union { uint4 u; __hip_bfloat16 h[8]; } st;
#pragma unroll
  for (int i = 0; i < 8; i++) {
    float vv = (f[i] - mu) * inv * w[gi * 8 + i] + b[gi * 8 + i];
    vv = (vv > 0.f) ? vv : (__expf(vv) - 1.f);
    st.h[i] = f2b(vv);
  }
  *(uint4*)(o + basei) = st.u;
}

// ---------------- MFMA GEMM: 64 x 256 tile, BK=32, dbuf LDS, 256 threads ----------------
// MODE 0: outB = ELU(GN8(A@W^T + bias)) bf16, Nc=256
// MODE 1: outB = A@W^T bf16; asrc/adst = row dots (plain stores), Nc=256
// MODE 2: outF = A@W^T + A2@W2^T + bias + bias2 fp32, Nc=512 (A2 bf16 staged)
// MODE 3: like 2 but second half streams Af32 (fp32 x) per-wave
template <int MODE>
__global__ __launch_bounds__(256, 3) void gemm_t(
    const __hip_bfloat16* __restrict__ A, const __hip_bfloat16* __restrict__ A2,
    const float* __restrict__ Af32,
    const __hip_bfloat16* __restrict__ W, const __hip_bfloat16* __restrict__ W2,
    const float* __restrict__ bias, const float* __restrict__ bias2,
    const float* __restrict__ gnw, const float* __restrict__ gnb,
    const float* __restrict__ avs, const float* __restrict__ avd,
    __hip_bfloat16* __restrict__ outB, float* __restrict__ outF,
    float* __restrict__ asrc, float* __restrict__ adst, int Nc, int Mreal) {
  const int tid = threadIdx.x;
  const int wn = tid >> 6, lane = tid & 63;
  const int l16 = lane & 15, quad = lane >> 4;
  const int rows0 = blockIdx.y * 64;
  const int col0 = blockIdx.x * 256;
  const int srow = tid >> 2, skc = (tid & 3) * 8;
  __shared__ __align__(16) __hip_bfloat16 sA[2][64 * 32];
  __shared__ __align__(16) __hip_bfloat16 sB[2][256 * 32];
  __shared__ float sRed[2][64][4];
  const int loA = tid * 8;  // = srow*32 + skc

  floatx4 acc[4][4];
#pragma unroll
  for (int a = 0; a < 4; ++a)
#pragma unroll
    for (int b = 0; b < 4; ++b) acc[a][b] = (floatx4){0.f, 0.f, 0.f, 0.f};

  const int NK = (MODE >= 2) ? 16 : 8;
  uint4 pa, pb[4];
  pa = *(const uint4*)(A + (size_t)(rows0 + srow) * 256 + skc);
#pragma unroll
  for (int h = 0; h < 4; ++h)
    pb[h] = *(const uint4*)(W + (size_t)(col0 + srow + h * 64) * 256 + skc);
  *(uint4*)(&sA[0][loA]) = pa;
#pragma unroll
  for (int h = 0; h < 4; ++h) *(uint4*)(&sB[0][loA + h * 2048]) = pb[h];
  __syncthreads();

#pragma unroll
  for (int kt = 0; kt < NK; ++kt) {
    const int cur = kt & 1, nxt = cur ^ 1;
    const int ktn = kt + 1;
    const bool nsec = (MODE >= 2) && (ktn >= 8);
    const bool nstageA = (ktn < NK) && !(MODE == 3 && nsec);
    if (ktn < NK) {
      const int kkn = (ktn & 7) * 32;
      const __hip_bfloat16* Wb = nsec ? W2 : W;
      if (nstageA) {
        const __hip_bfloat16* Ab = (MODE == 2 && nsec) ? A2 : A;
        pa = *(const uint4*)(Ab + (size_t)(rows0 + srow) * 256 + kkn + skc);
      }
#pragma unroll
      for (int h = 0; h < 4; ++h)
        pb[h] = *(const uint4*)(Wb + (size_t)(col0 + srow + h * 64) * 256 + kkn + skc);
    }
    bf16x8 af[4], bfr[4];
    if (MODE == 3 && kt >= 8) {
      const int kk = (kt & 7) * 32;
#pragma unroll
      for (int ri = 0; ri < 4; ++ri) {
        int row = min(rows0 + ri * 16 + l16, Mreal - 1);
        af[ri] = cvt8(Af32 + (size_t)row * 256 + kk + quad * 8);
      }
    } else {
#pragma unroll
      for (int ri = 0; ri < 4; ++ri)
        af[ri] = *(const bf16x8*)(&sA[cur][(ri * 16 + l16) * 32 + quad * 8]);
    }
#pragma unroll
    for (int ci = 0; ci < 4; ++ci)
      bfr[ci] = *(const bf16x8*)(&sB[cur][(wn * 64 + ci * 16 + l16) * 32 + quad * 8]);
#pragma unroll
    for (int ri = 0; ri < 4; ++ri)
#pragma unroll
      for (int ci = 0; ci < 4; ++ci)
        acc[ri][ci] = __builtin_amdgcn_mfma_f32_16x16x32_bf16(af[ri], bfr[ci], acc[ri][ci], 0, 0, 0);
    if (ktn < NK) {
      if (nstageA) *(uint4*)(&sA[nxt][loA]) = pa;
#pragma unroll
      for (int h = 0; h < 4; ++h) *(uint4*)(&sB[nxt][loA + h * 2048]) = pb[h];
    }
    __syncthreads();
  }

  // C/D layout: col = col0 + wn*64 + ci*16 + l16; row = rows0 + ri*16 + quad*4 + i
  if (MODE == 0) {
#pragma unroll
    for (int ri = 0; ri < 4; ++ri)
#pragma unroll
      for (int ci = 0; ci < 4; ++ci) {
        int col = col0 + wn * 64 + ci * 16 + l16;
        float bs = bias[col], gw = gnw[col], gb = gnb[col];
#pragma unroll
        for (int i = 0; i < 4; ++i) {
          float v = acc[ri][ci][i] + bs;
          float s = v;
          s += __shfl_xor(s, 1, 64); s += __shfl_xor(s, 2, 64); s += __shfl_xor(s, 4, 64);
          float mu = s * 0.125f, d = v - mu;
          float q = d * d;
          q += __shfl_xor(q, 1, 64); q += __shfl_xor(q, 2, 64); q += __shfl_xor(q, 4, 64);
          float r = d * rsqrtf(q * 0.125f + 1e-5f) * gw + gb;
          r = (r > 0.f) ? r : (__expf(r) - 1.f);
          outB[(size_t)(rows0 + ri * 16 + quad * 4 + i) * 256 + col] = f2b(r);
        }
      }
  } else if (MODE == 1) {
#pragma unroll
    for (int ri = 0; ri < 4; ++ri) {
      float ps[4] = {0.f, 0.f, 0.f, 0.f}, pd[4] = {0.f, 0.f, 0.f, 0.f};
#pragma unroll
      for (int ci = 0; ci < 4; ++ci) {
        int col = col0 + wn * 64 + ci * 16 + l16;
        float wsv = avs[col], wdv = avd[col];
#pragma unroll
        for (int i = 0; i < 4; ++i) {
          float v = acc[ri][ci][i];
          outB[(size_t)(rows0 + ri * 16 + quad * 4 + i) * 256 + col] = f2b(v);
          ps[i] += v * wsv; pd[i] += v * wdv;
        }
      }
#pragma unroll
      for (int i = 0; i < 4; ++i) {
        ps[i] += __shfl_xor(ps[i], 1, 64); ps[i] += __shfl_xor(ps[i], 2, 64);
        ps[i] += __shfl_xor(ps[i], 4, 64); ps[i] += __shfl_xor(ps[i], 8, 64);
        pd[i] += __shfl_xor(pd[i], 1, 64); pd[i] += __shfl_xor(pd[i], 2, 64);
        pd[i] += __shfl_xor(pd[i], 4, 64); pd[i] += __shfl_xor(pd[i], 8, 64);
        if (l16 == 0) {
          int r = ri * 16 + quad * 4 + i;
          sRed[0][r][wn] = ps[i];
          sRed[1][r][wn] = pd[i];
        }
      }
    }
    __syncthreads();
    if (tid < 128) {
      int arr = tid >> 6, r = tid & 63;
      float v = sRed[arr][r][0] + sRed[arr][r][1] + sRed[arr][r][2] + sRed[arr][r][3];
      (arr ? adst : asrc)[rows0 + r] = v;
    }
  } else {
#pragma unroll
    for (int ri = 0; ri < 4; ++ri)
#pragma unroll
      for (int ci = 0; ci < 4; ++ci) {
        int col = col0 + wn * 64 + ci * 16 + l16;
        float bs = bias[col] + bias2[col];
#pragma unroll
        for (int i = 0; i < 4; ++i) {
          int row = rows0 + ri * 16 + quad * 4 + i;
          if (row < Mreal) outF[(size_t)row * Nc + col] = acc[ri][ci][i] + bs;
        }
      }
  }
}

// ---------------- CSR build ----------------
__global__ void zero_k(int* p, int n) {
  int i = blockIdx.x * blockDim.x + threadIdx.x;
  if (i < n) p[i] = 0;
}

__global__ void count_deg_k(const int* __restrict__ ei, int E, int NN, int* __restrict__ counts) {
  int e = blockIdx.x * blockDim.x + threadIdx.x;
  if (e >= E + NN) return;
  int d = (e < E) ? ei[E + e] : (e - E);
  if ((unsigned)d >= (unsigned)NN) d = 0;
  atomicAdd(&counts[d], 1);
}

__global__ __launch_bounds__(1024) void scan_blk_k(const int* __restrict__ counts,
                                                   int* __restrict__ indptr,
                                                   int* __restrict__ bsums, int NN) {
  __shared__ int wsum[16];
  int t = threadIdx.x, idx = blockIdx.x * 1024 + t;
  int lane = t & 63, wid = t >> 6;
  int v = (idx < NN) ? counts[idx] : 0;
  int s = v;
#pragma unroll
  for (int off = 1; off < 64; off <<= 1) {
    int u = __shfl_up(s, off, 64);
    if (lane >= off) s += u;
  }
  if (lane == 63) wsum[wid] = s;
  __syncthreads();
  if (t == 0) {
    int run = 0;
#pragma unroll
    for (int i = 0; i < 16; i++) { int u = wsum[i]; wsum[i] = run; run += u; }
    bsums[blockIdx.x] = run;
  }
  __syncthreads();
  if (idx < NN) indptr[idx] = s - v + wsum[wid];
}

__global__ void scan_top_k(int* bsums, int nb) {
  if (threadIdx.x == 0) {
    int run = 0;
    for (int i = 0; i < nb; i++) { int t = bsums[i]; bsums[i] = run; run += t; }
  }
}

__global__ __launch_bounds__(1024) void scan_add_k(int* __restrict__ indptr, int* __restrict__ fill,
                                                   const int* __restrict__ bsums, int NN, int ET) {
  int idx = blockIdx.x * 1024 + threadIdx.x;
  if (idx < NN) {
    int v = indptr[idx] + bsums[blockIdx.x];
    indptr[idx] = v; fill[idx] = v;
  }
  if (idx == 0) indptr[NN] = ET;
}

__global__ void fill_csr_k(const int* __restrict__ ei, int E, int NN,
                           int* __restrict__ fill, int* __restrict__ csr, int ET) {
  int e = blockIdx.x * blockDim.x + threadIdx.x;
  if (e >= E + NN) return;
  int s, d;
  if (e < E) { s = ei[e]; d = ei[E + e]; } else { s = e - E; d = e - E; }
  if ((unsigned)d >= (unsigned)NN) d = 0;
  if ((unsigned)s >= (unsigned)NN) s = 0;
  int slot = atomicAdd(&fill[d], 1);
  if ((unsigned)slot < (unsigned)ET) csr[slot] = s;
}

// ---------------- GAT agg: wave/node, no-max softmax, LDS-staged (sid,w), no shfl loop ----
// Per 64-edge chunk: each lane computes its edge's softmax weight once, stages (sid,w) as
// one b64 into per-wave LDS; main loop does broadcast ds_read_b64 (2 unique addrs/wave,
// conflict-free) + 4 independent 16B gathers + float2 (pk_fma) accumulate.
// Pad slots carry w=0, sid=0 (row 0 gather, L1-hot, adds 0).
__global__ __launch_bounds__(256) void gat_agg_gn_k(
    const __hip_bfloat16* __restrict__ h, const float* __restrict__ asrc,
    const float* __restrict__ adst, const int* __restrict__ indptr,
    const int* __restrict__ csr, const float* __restrict__ gbias,
    const float* __restrict__ gnw, const float* __restrict__ gnb,
    __hip_bfloat16* __restrict__ outp, int NN, int ET) {
  __shared__ __align__(16) unsigned long long sew[4][64];
  const int wid = threadIdx.x >> 6;
  const int n = blockIdx.x * 4 + wid;
  if (n >= NN) return;
  const int lane = threadIdx.x & 63;
  const int half = lane >> 5, l32 = lane & 31;
  int beg = indptr[n], end = indptr[n + 1];
  beg = max(0, min(beg, ET));
  end = max(beg, min(end, ET));
  const int deg = end - beg;
  const float adn = adst[n];
  floatx2 a0 = {0.f, 0.f}, a1 = {0.f, 0.f}, a2 = {0.f, 0.f}, a3 = {0.f, 0.f};
  float lw = 0.f;

  for (int cb = 0; cb < deg; cb += 64) {
    int j = cb + lane;
    int sid = 0; float w = 0.f;
    if (j < deg) {
      sid = csr[beg + j];
      if ((unsigned)sid >= (unsigned)NN) sid = 0;
      float e = asrc[sid] + adn;
      e = (e > 0.f) ? e : 0.2f * e;                  // leaky_relu 0.2
      e = fminf(fmaxf(e, -60.f), 60.f);              // softmax shift-invariant; clamp
      w = __expf(e);
    }
    lw += w;
    sew[wid][lane] = (unsigned)sid | ((unsigned long long)__float_as_uint(w) << 32);
    // same-wave LDS produce/consume: ordered via lgkmcnt, no barrier needed
    int cnt = min(64, deg - cb);
    for (int t = 0; t < cnt; t += 8) {
      int s[4]; float wt[4]; uint4 hv[4];
#pragma unroll
      for (int u = 0; u < 4; ++u) {
        unsigned long long pv = sew[wid][t + u * 2 + half];
        s[u] = (int)(unsigned)pv;
        wt[u] = __uint_as_float((unsigned)(pv >> 32));
      }
#pragma unroll
      for (int u = 0; u < 4; ++u)
        hv[u] = *(const uint4*)(h + (size_t)s[u] * 256 + l32 * 8);
#pragma unroll
      for (int u = 0; u < 4; ++u) {
        floatx2 wv = {wt[u], wt[u]};
        floatx2 p;
        p[0] = bits2f(hv[u].x & 0xffffu); p[1] = bits2f(hv[u].x >> 16);
        a0 += wv * p;
        p[0] = bits2f(hv[u].y & 0xffffu); p[1] = bits2f(hv[u].y >> 16);
        a1 += wv * p;
        p[0] = bits2f(hv[u].z & 0xffffu); p[1] = bits2f(hv[u].z >> 16);
        a2 += wv * p;
        p[0] = bits2f(hv[u].w & 0xffffu); p[1] = bits2f(hv[u].w >> 16);
        a3 += wv * p;
      }
    }
  }
  float r8[8] = {a0[0], a0[1], a1[0], a1[1], a2[0], a2[1], a3[0], a3[1]};
#pragma unroll
  for (int i = 0; i < 8; ++i) r8[i] += __shfl_xor(r8[i], 32, 64);
#pragma unroll
  for (int m = 32; m >= 1; m >>= 1) lw += __shfl_xor(lw, m, 64);
  if (half == 0) {
    float inv = 1.f / (lw + 1e-16f);
    int c0 = l32 * 8;                                // lane owns one full GN group of 8
    float v[8], mu = 0.f;
#pragma unroll
    for (int i = 0; i < 8; ++i) { v[i] = r8[i] * inv + gbias[c0 + i]; mu += v[i]; }
    mu *= 0.125f;
    float q = 0.f;
#pragma unroll
    for (int i = 0; i < 8; ++i) { float d = v[i] - mu; q += d * d; }
    float rs = rsqrtf(q * 0.125f + 1e-5f);
    union { uint4 u; __hip_bfloat16 b[8]; } st;
#pragma unroll
    for (int i = 0; i < 8; ++i) {
      float r = (v[i] - mu) * rs * gnw[c0 + i] + gnb[c0 + i];
      r = (r > 0.f) ? r : (__expf(r) - 1.f);
      st.b[i] = f2b(r);
    }
    *(uint4*)(outp + (size_t)n * 256 + c0) = st.u;
  }
}

// ---------------- launch ----------------
extern "C" void kernel_launch(void* const* d_in, const int* in_sizes, int n_in,
                              void* d_out, int out_size, void* d_ws, size_t ws_size,
                              hipStream_t stream) {
  const float* x      = (const float*)d_in[0];
  const int*   ei     = (const int*)d_in[1];
  const float* pre_w  = (const float*)d_in[2];
  const float* pre_b  = (const float*)d_in[3];
  const float* lin1_b = (const float*)d_in[5];
  const float* n1_w   = (const float*)d_in[6];
  const float* n1_b   = (const float*)d_in[7];
  const float* g1_as  = (const float*)d_in[9];
  const float* g1_ad  = (const float*)d_in[10];
  const float* g1_b   = (const float*)d_in[11];
  const float* n2_w   = (const float*)d_in[12];
  const float* n2_b   = (const float*)d_in[13];
  const float* g2_as  = (const float*)d_in[15];
  const float* g2_ad  = (const float*)d_in[16];
  const float* g2_b   = (const float*)d_in[17];
  const float* n3_w   = (const float*)d_in[18];
  const float* n3_b   = (const float*)d_in[19];
  const float* lin2_b = (const float*)d_in[21];
  const float* skip_b = (const float*)d_in[23];
  float* out = (float*)d_out;

  const int C_IN  = in_sizes[2];          // 256
  const int NN    = in_sizes[0] / C_IN;   // 40000
  const int E     = in_sizes[1] / 2;      // 640000
  const int ET    = E + NN;
  const int C_OUT = in_sizes[21];         // 512
  const int NP    = (NN + 127) & ~127;    // 40064

  __hip_bfloat16* D0 = (__hip_bfloat16*)d_out;        // bf16 scratch in d_out
  __hip_bfloat16* D1 = D0 + (size_t)NP * 256;

  char* basep = (char*)d_ws;
  size_t o = 0;
  auto alloc = [&](size_t bytes) { size_t r = o; o += (bytes + 255) & ~(size_t)255; return r; };
  __hip_bfloat16* Y      = (__hip_bfloat16*)(basep + alloc((size_t)NP * 256 * 2));
  __hip_bfloat16* Wcat   = (__hip_bfloat16*)(basep + alloc((size_t)458752 * 2));
  float*          asrc   = (float*)(basep + alloc((size_t)NP * 4));
  float*          adst   = (float*)(basep + alloc((size_t)NP * 4));
  int*            indptr = (int*)(basep + alloc((size_t)(NN + 1) * 4));
  int*            counts = (int*)(basep + alloc((size_t)NN * 4));
  int*            fill   = (int*)(basep + alloc((size_t)NN * 4));
  int*            bsums  = (int*)(basep + alloc(256));
  int*            csr    = (int*)(basep + alloc((size_t)ET * 4));
  size_t base_need = o;
  size_t xb_need = ((size_t)NP * 256 * 2 + 255) & ~(size_t)255;
  const bool use_xb = (ws_size >= base_need + xb_need);
  __hip_bfloat16* xb = use_xb ? (__hip_bfloat16*)(basep + alloc(xb_need)) : nullptr;

  __hip_bfloat16* Wlin1 = Wcat;
  __hip_bfloat16* Wg1   = Wcat + 65536;
  __hip_bfloat16* Wg2   = Wcat + 131072;
  __hip_bfloat16* Wlin2 = Wcat + 196608;
  __hip_bfloat16* Wskip = Wcat + 327680;

  dim3 blk(256);
  const int nb = (NN + 1023) / 1024;      // 40

  conv_w_k<<<(458752 / 4 + 255) / 256, blk, 0, stream>>>(
      (const float*)d_in[4], (const float*)d_in[8], (const float*)d_in[14],
      (const float*)d_in[20], (const float*)d_in[22], Wcat);
  zero_k<<<(NN + 255) / 256, blk, 0, stream>>>(counts, NN);
  count_deg_k<<<(ET + 255) / 256, blk, 0, stream>>>(ei, E, NN, counts);
  scan_blk_k<<<nb, 1024, 0, stream>>>(counts, indptr, bsums, NN);
  scan_top_k<<<1, 64, 0, stream>>>(bsums, nb);
  scan_add_k<<<nb, 1024, 0, stream>>>(indptr, fill, bsums, NN, ET);
  fill_csr_k<<<(ET + 255) / 256, blk, 0, stream>>>(ei, E, NN, fill, csr, ET);

  gn_elu_k<<<(NN * 32 + 255) / 256, blk, 0, stream>>>(x, pre_w, pre_b, D0, xb, NN * 32);
  // lin1 + GN1 + ELU
  gemm_t<0><<<dim3(1, NP / 64), blk, 0, stream>>>(D0, nullptr, nullptr, Wlin1, nullptr,
      lin1_b, nullptr, n1_w, n1_b, nullptr, nullptr, Y, nullptr, nullptr, nullptr, 256, NN);
  // GAT1
  gemm_t<1><<<dim3(1, NP / 64), blk, 0, stream>>>(Y, nullptr, nullptr, Wg1, nullptr,
      nullptr, nullptr, nullptr, nullptr, g1_as, g1_ad, D0, nullptr, asrc, adst, 256, NN);
  gat_agg_gn_k<<<NN / 4, blk, 0, stream>>>(D0, asrc, adst, indptr, csr, g1_b, n2_w, n2_b, D1, NN, ET);
  // GAT2
  gemm_t<1><<<dim3(1, NP / 64), blk, 0, stream>>>(D1, nullptr, nullptr, Wg2, nullptr,
      nullptr, nullptr, nullptr, nullptr, g2_as, g2_ad, D0, nullptr, asrc, adst, 256, NN);
  gat_agg_gn_k<<<NN / 4, blk, 0, stream>>>(D0, asrc, adst, indptr, csr, g2_b, n3_w, n3_b, Y, NN, ET);
  // lin2 + skip fused -> out (K=512)
  if (use_xb) {
    gemm_t<2><<<dim3(C_OUT / 256, NP / 64), blk, 0, stream>>>(Y, xb, nullptr, Wlin2, Wskip,
        lin2_b, skip_b, nullptr, nullptr, nullptr, nullptr, nullptr, out, nullptr, nullptr, C_OUT, NN);
  } else {
    gemm_t<3><<<dim3(C_OUT / 256, NP / 64), blk, 0, stream>>>(Y, nullptr, x, Wlin2, Wskip,
        lin2_b, skip_b, nullptr, nullptr, nullptr, nullptr, nullptr, out, nullptr, nullptr, C_OUT, NN);
  }
}

// Round 4
// 427.292 us; speedup vs baseline: 1.4254x; 1.0039x over previous
//
#include <hip/hip_runtime.h>
#include <hip/hip_bf16.h>

// GraphResBlock on MI355X — round 9.
// GEMMs: 64row x 256col tiles, BK=32, dbuf LDS, 4 waves (each 64x64), MFMA bf16,
//   staging now via __builtin_amdgcn_global_load_lds width=16 (direct HBM->LDS DMA,
//   m97 schedule: issue into nxt buffer after barrier, compute cur, barrier drains vmcnt).
// Final GEMM reads pre-converted bf16 xb (MODE 2) if ws_size permits, else streams fp32 (MODE 3).
// GAT agg: round-3 structure kept (LDS-staged (sid,w), 4-deep 16B gathers, pk_fma, lane-local GN).
// CSR: parallel 3-stage scan.

typedef __bf16 bf16x8 __attribute__((ext_vector_type(8)));
typedef float floatx4 __attribute__((ext_vector_type(4)));
typedef float floatx2 __attribute__((ext_vector_type(2)));

__device__ __forceinline__ __hip_bfloat16 f2b(float f) { return __float2bfloat16(f); }
__device__ __forceinline__ float bits2f(unsigned u) { return __uint_as_float(u << 16); }

// async global->LDS, 16B per lane; lds base must be wave-uniform (HW: base + lane*16)
__device__ __forceinline__ void gl_lds16(const __hip_bfloat16* g, __hip_bfloat16* l) {
  __builtin_amdgcn_global_load_lds(
      (const __attribute__((address_space(1))) void*)g,
      (__attribute__((address_space(3))) void*)l, 16, 0, 0);
}

__device__ __forceinline__ bf16x8 cvt8(const float* p) {
  float4 a = *(const float4*)p, b = *(const float4*)(p + 4);
  bf16x8 r;
  r[0] = (__bf16)a.x; r[1] = (__bf16)a.y; r[2] = (__bf16)a.z; r[3] = (__bf16)a.w;
  r[4] = (__bf16)b.x; r[5] = (__bf16)b.y; r[6] = (__bf16)b.z; r[7] = (__bf16)b.w;
  return r;
}

// ---------------- weight fp32 -> bf16 pack ----------------
__global__ __launch_bounds__(256) void conv_w_k(
    const float* __restrict__ s0, const float* __restrict__ s1,
    const float* __restrict__ s2, const float* __restrict__ s3,
    const float* __restrict__ s4, __hip_bfloat16* __restrict__ d) {
  int i = (blockIdx.x * 256 + threadIdx.x) * 4;
  if (i >= 458752) return;
  const float* s; int off;
  if      (i < 65536)  { s = s0; off = 0; }
  else if (i < 131072) { s = s1; off = 65536; }
  else if (i < 196608) { s = s2; off = 131072; }
  else if (i < 327680) { s = s3; off = 196608; }
  else                 { s = s4; off = 327680; }
  float4 v = *(const float4*)(s + (i - off));
  union { ushort4 u; __hip_bfloat16 h[4]; } st;
  st.h[0] = f2b(v.x); st.h[1] = f2b(v.y); st.h[2] = f2b(v.z); st.h[3] = f2b(v.w);
  *(ushort4*)(d + i) = st.u;
}

// ---------------- pre GroupNorm(8) + ELU (+ optional raw x -> bf16) ----------------
__global__ __launch_bounds__(256) void gn_elu_k(
    const float* __restrict__ x, const float* __restrict__ w, const float* __restrict__ b,
    __hip_bfloat16* __restrict__ o, __hip_bfloat16* __restrict__ xb, int ng) {
  int g = blockIdx.x * 256 + threadIdx.x;
  if (g >= ng) return;
  int gi = g & 31;
  size_t basei = (size_t)g * 8;
  float4 u0 = *(const float4*)(x + basei), u1 = *(const float4*)(x + basei + 4);
  float f[8] = {u0.x, u0.y, u0.z, u0.w, u1.x, u1.y, u1.z, u1.w};
  if (xb) {
    union { uint4 u; __hip_bfloat16 h[8]; } xs;
#pragma unroll
    for (int i = 0; i < 8; i++) xs.h[i] = f2b(f[i]);
    *(uint4*)(xb + basei) = xs.u;
  }
  float mu = 0.f;
#pragma unroll
  for (int i = 0; i < 8; i++) mu += f[i];
  mu *= 0.125f;
  float var = 0.f;
#pragma unroll
  for (int i = 0; i < 8; i++) { float d = f[i] - mu; var += d * d; }
  float inv = rsqrtf(var * 0.125f + 1e-5f);
  union { uint4 u; __hip_bfloat16 h[8]; } st;
#pragma unroll
  for (int i = 0; i < 8; i++) {
    float vv = (f[i] - mu) * inv * w[gi * 8 + i] + b[gi * 8 + i];
    vv = (vv > 0.f) ? vv : (__expf(vv) - 1.f);
    st.h[i] = f2b(vv);
  }
  *(uint4*)(o + basei) = st.u;
}

// ---------------- MFMA GEMM: 64 x 256 tile, BK=32, dbuf LDS, 256 threads ----------------
// MODE 0: outB = ELU(GN8(A@W^T + bias)) bf16, Nc=256
// MODE 1: outB = A@W^T bf16; asrc/adst = row dots (plain stores), Nc=256
// MODE 2: outF = A@W^T + A2@W2^T + bias + bias2 fp32, Nc=512 (A2 bf16 staged)
// MODE 3: like 2 but second half streams Af32 (fp32 x) per-wave
template <int MODE>
__global__ __launch_bounds__(256, 3) void gemm_t(
    const __hip_bfloat16* __restrict__ A, const __hip_bfloat16* __restrict__ A2,
    const float* __restrict__ Af32,
    const __hip_bfloat16* __restrict__ W, const __hip_bfloat16* __restrict__ W2,
    const float* __restrict__ bias, const float* __restrict__ bias2,
    const float* __restrict__ gnw, const float* __restrict__ gnb,
    const float* __restrict__ avs, const float* __restrict__ avd,
    __hip_bfloat16* __restrict__ outB, float* __restrict__ outF,
    float* __restrict__ asrc, float* __restrict__ adst, int Nc, int Mreal) {
  const int tid = threadIdx.x;
  const int wn = tid >> 6, lane = tid & 63;
  const int l16 = lane & 15, quad = lane >> 4;
  const int rows0 = blockIdx.y * 64;
  const int col0 = blockIdx.x * 256;
  const int srow = tid >> 2, skc = (tid & 3) * 8;
  __shared__ __align__(16) __hip_bfloat16 sA[2][64 * 32];
  __shared__ __align__(16) __hip_bfloat16 sB[2][256 * 32];
  __shared__ float sRed[2][64][4];
  const int wbase = wn << 9;  // wave-uniform LDS segment base (elems); lane slot = +lane*8

  floatx4 acc[4][4];
#pragma unroll
  for (int a = 0; a < 4; ++a)
#pragma unroll
    for (int b = 0; b < 4; ++b) acc[a][b] = (floatx4){0.f, 0.f, 0.f, 0.f};

  const int NK = (MODE >= 2) ? 16 : 8;

  // async stage of K-tile kt into LDS buffer buf (per-lane global addr, linear LDS dest)
  auto stage = [&](int buf, int kt) {
    const int kk = (kt & 7) * 32;
    const bool sec = (MODE >= 2) && (kt >= 8);
    const __hip_bfloat16* Wb = sec ? W2 : W;
    if (!(MODE == 3 && sec)) {
      const __hip_bfloat16* Ab = (MODE == 2 && sec) ? A2 : A;
      gl_lds16(Ab + (size_t)(rows0 + srow) * 256 + kk + skc, &sA[buf][wbase]);
    }
#pragma unroll
    for (int h = 0; h < 4; ++h)
      gl_lds16(Wb + (size_t)(col0 + srow + h * 64) * 256 + kk + skc,
               &sB[buf][wbase + h * 2048]);
  };

  stage(0, 0);
  __syncthreads();

#pragma unroll
  for (int kt = 0; kt < NK; ++kt) {
    const int cur = kt & 1, nxt = cur ^ 1;
    if (kt + 1 < NK) stage(nxt, kt + 1);
    bf16x8 af[4], bfr[4];
    if (MODE == 3 && kt >= 8) {
      const int kk = (kt & 7) * 32;
#pragma unroll
      for (int ri = 0; ri < 4; ++ri) {
        int row = min(rows0 + ri * 16 + l16, Mreal - 1);
        af[ri] = cvt8(Af32 + (size_t)row * 256 + kk + quad * 8);
      }
    } else {
#pragma unroll
      for (int ri = 0; ri < 4; ++ri)
        af[ri] = *(const bf16x8*)(&sA[cur][(ri * 16 + l16) * 32 + quad * 8]);
    }
#pragma unroll
    for (int ci = 0; ci < 4; ++ci)
      bfr[ci] = *(const bf16x8*)(&sB[cur][(wn * 64 + ci * 16 + l16) * 32 + quad * 8]);
#pragma unroll
    for (int ri = 0; ri < 4; ++ri)
#pragma unroll
      for (int ci = 0; ci < 4; ++ci)
        acc[ri][ci] = __builtin_amdgcn_mfma_f32_16x16x32_bf16(af[ri], bfr[ci], acc[ri][ci], 0, 0, 0);
    __syncthreads();  // drains vmcnt (nxt-stage) + lgkm; nxt ready for kt+1
  }

  // C/D layout: col = col0 + wn*64 + ci*16 + l16; row = rows0 + ri*16 + quad*4 + i
  if (MODE == 0) {
#pragma unroll
    for (int ri = 0; ri < 4; ++ri)
#pragma unroll
      for (int ci = 0; ci < 4; ++ci) {
        int col = col0 + wn * 64 + ci * 16 + l16;
        float bs = bias[col], gw = gnw[col], gb = gnb[col];
#pragma unroll
        for (int i = 0; i < 4; ++i) {
          float v = acc[ri][ci][i] + bs;
          float s = v;
          s += __shfl_xor(s, 1, 64); s += __shfl_xor(s, 2, 64); s += __shfl_xor(s, 4, 64);
          float mu = s * 0.125f, d = v - mu;
          float q = d * d;
          q += __shfl_xor(q, 1, 64); q += __shfl_xor(q, 2, 64); q += __shfl_xor(q, 4, 64);
          float r = d * rsqrtf(q * 0.125f + 1e-5f) * gw + gb;
          r = (r > 0.f) ? r : (__expf(r) - 1.f);
          outB[(size_t)(rows0 + ri * 16 + quad * 4 + i) * 256 + col] = f2b(r);
        }
      }
  } else if (MODE == 1) {
#pragma unroll
    for (int ri = 0; ri < 4; ++ri) {
      float ps[4] = {0.f, 0.f, 0.f, 0.f}, pd[4] = {0.f, 0.f, 0.f, 0.f};
#pragma unroll
      for (int ci = 0; ci < 4; ++ci) {
        int col = col0 + wn * 64 + ci * 16 + l16;
        float wsv = avs[col], wdv = avd[col];
#pragma unroll
        for (int i = 0; i < 4; ++i) {
          float v = acc[ri][ci][i];
          outB[(size_t)(rows0 + ri * 16 + quad * 4 + i) * 256 + col] = f2b(v);
          ps[i] += v * wsv; pd[i] += v * wdv;
        }
      }
#pragma unroll
      for (int i = 0; i < 4; ++i) {
        ps[i] += __shfl_xor(ps[i], 1, 64); ps[i] += __shfl_xor(ps[i], 2, 64);
        ps[i] += __shfl_xor(ps[i], 4, 64); ps[i] += __shfl_xor(ps[i], 8, 64);
        pd[i] += __shfl_xor(pd[i], 1, 64); pd[i] += __shfl_xor(pd[i], 2, 64);
        pd[i] += __shfl_xor(pd[i], 4, 64); pd[i] += __shfl_xor(pd[i], 8, 64);
        if (l16 == 0) {
          int r = ri * 16 + quad * 4 + i;
          sRed[0][r][wn] = ps[i];
          sRed[1][r][wn] = pd[i];
        }
      }
    }
    __syncthreads();
    if (tid < 128) {
      int arr = tid >> 6, r = tid & 63;
      float v = sRed[arr][r][0] + sRed[arr][r][1] + sRed[arr][r][2] + sRed[arr][r][3];
      (arr ? adst : asrc)[rows0 + r] = v;
    }
  } else {
#pragma unroll
    for (int ri = 0; ri < 4; ++ri)
#pragma unroll
      for (int ci = 0; ci < 4; ++ci) {
        int col = col0 + wn * 64 + ci * 16 + l16;
        float bs = bias[col] + bias2[col];
#pragma unroll
        for (int i = 0; i < 4; ++i) {
          int row = rows0 + ri * 16 + quad * 4 + i;
          if (row < Mreal) outF[(size_t)row * Nc + col] = acc[ri][ci][i] + bs;
        }
      }
  }
}

// ---------------- CSR build ----------------
__global__ void zero_k(int* p, int n) {
  int i = blockIdx.x * blockDim.x + threadIdx.x;
  if (i < n) p[i] = 0;
}

__global__ void count_deg_k(const int* __restrict__ ei, int E, int NN, int* __restrict__ counts) {
  int e = blockIdx.x * blockDim.x + threadIdx.x;
  if (e >= E + NN) return;
  int d = (e < E) ? ei[E + e] : (e - E);
  if ((unsigned)d >= (unsigned)NN) d = 0;
  atomicAdd(&counts[d], 1);
}

__global__ __launch_bounds__(1024) void scan_blk_k(const int* __restrict__ counts,
                                                   int* __restrict__ indptr,
                                                   int* __restrict__ bsums, int NN) {
  __shared__ int wsum[16];
  int t = threadIdx.x, idx = blockIdx.x * 1024 + t;
  int lane = t & 63, wid = t >> 6;
  int v = (idx < NN) ? counts[idx] : 0;
  int s = v;
#pragma unroll
  for (int off = 1; off < 64; off <<= 1) {
    int u = __shfl_up(s, off, 64);
    if (lane >= off) s += u;
  }
  if (lane == 63) wsum[wid] = s;
  __syncthreads();
  if (t == 0) {
    int run = 0;
#pragma unroll
    for (int i = 0; i < 16; i++) { int u = wsum[i]; wsum[i] = run; run += u; }
    bsums[blockIdx.x] = run;
  }
  __syncthreads();
  if (idx < NN) indptr[idx] = s - v + wsum[wid];
}

__global__ void scan_top_k(int* bsums, int nb) {
  if (threadIdx.x == 0) {
    int run = 0;
    for (int i = 0; i < nb; i++) { int t = bsums[i]; bsums[i] = run; run += t; }
  }
}

__global__ __launch_bounds__(1024) void scan_add_k(int* __restrict__ indptr, int* __restrict__ fill,
                                                   const int* __restrict__ bsums, int NN, int ET) {
  int idx = blockIdx.x * 1024 + threadIdx.x;
  if (idx < NN) {
    int v = indptr[idx] + bsums[blockIdx.x];
    indptr[idx] = v; fill[idx] = v;
  }
  if (idx == 0) indptr[NN] = ET;
}

__global__ void fill_csr_k(const int* __restrict__ ei, int E, int NN,
                           int* __restrict__ fill, int* __restrict__ csr, int ET) {
  int e = blockIdx.x * blockDim.x + threadIdx.x;
  if (e >= E + NN) return;
  int s, d;
  if (e < E) { s = ei[e]; d = ei[E + e]; } else { s = e - E; d = e - E; }
  if ((unsigned)d >= (unsigned)NN) d = 0;
  if ((unsigned)s >= (unsigned)NN) s = 0;
  int slot = atomicAdd(&fill[d], 1);
  if ((unsigned)slot < (unsigned)ET) csr[slot] = s;
}

// ---------------- GAT agg: wave/node, no-max softmax, LDS-staged (sid,w), no shfl loop ----
__global__ __launch_bounds__(256) void gat_agg_gn_k(
    const __hip_bfloat16* __restrict__ h, const float* __restrict__ asrc,
    const float* __restrict__ adst, const int* __restrict__ indptr,
    const int* __restrict__ csr, const float* __restrict__ gbias,
    const float* __restrict__ gnw, const float* __restrict__ gnb,
    __hip_bfloat16* __restrict__ outp, int NN, int ET) {
  __shared__ __align__(16) unsigned long long sew[4][64];
  const int wid = threadIdx.x >> 6;
  const int n = blockIdx.x * 4 + wid;
  if (n >= NN) return;
  const int lane = threadIdx.x & 63;
  const int half = lane >> 5, l32 = lane & 31;
  int beg = indptr[n], end = indptr[n + 1];
  beg = max(0, min(beg, ET));
  end = max(beg, min(end, ET));
  const int deg = end - beg;
  const float adn = adst[n];
  floatx2 a0 = {0.f, 0.f}, a1 = {0.f, 0.f}, a2 = {0.f, 0.f}, a3 = {0.f, 0.f};
  float lw = 0.f;

  for (int cb = 0; cb < deg; cb += 64) {
    int j = cb + lane;
    int sid = 0; float w = 0.f;
    if (j < deg) {
      sid = csr[beg + j];
      if ((unsigned)sid >= (unsigned)NN) sid = 0;
      float e = asrc[sid] + adn;
      e = (e > 0.f) ? e : 0.2f * e;                  // leaky_relu 0.2
      e = fminf(fmaxf(e, -60.f), 60.f);              // softmax shift-invariant; clamp
      w = __expf(e);
    }
    lw += w;
    sew[wid][lane] = (unsigned)sid | ((unsigned long long)__float_as_uint(w) << 32);
    // same-wave LDS produce/consume: ordered via lgkmcnt, no barrier needed
    int cnt = min(64, deg - cb);
    for (int t = 0; t < cnt; t += 8) {
      int s[4]; float wt[4]; uint4 hv[4];
#pragma unroll
      for (int u = 0; u < 4; ++u) {
        unsigned long long pv = sew[wid][t + u * 2 + half];
        s[u] = (int)(unsigned)pv;
        wt[u] = __uint_as_float((unsigned)(pv >> 32));
      }
#pragma unroll
      for (int u = 0; u < 4; ++u)
        hv[u] = *(const uint4*)(h + (size_t)s[u] * 256 + l32 * 8);
#pragma unroll
      for (int u = 0; u < 4; ++u) {
        floatx2 wv = {wt[u], wt[u]};
        floatx2 p;
        p[0] = bits2f(hv[u].x & 0xffffu); p[1] = bits2f(hv[u].x >> 16);
        a0 += wv * p;
        p[0] = bits2f(hv[u].y & 0xffffu); p[1] = bits2f(hv[u].y >> 16);
        a1 += wv * p;
        p[0] = bits2f(hv[u].z & 0xffffu); p[1] = bits2f(hv[u].z >> 16);
        a2 += wv * p;
        p[0] = bits2f(hv[u].w & 0xffffu); p[1] = bits2f(hv[u].w >> 16);
        a3 += wv * p;
      }
    }
  }
  float r8[8] = {a0[0], a0[1], a1[0], a1[1], a2[0], a2[1], a3[0], a3[1]};
#pragma unroll
  for (int i = 0; i < 8; ++i) r8[i] += __shfl_xor(r8[i], 32, 64);
#pragma unroll
  for (int m = 32; m >= 1; m >>= 1) lw += __shfl_xor(lw, m, 64);
  if (half == 0) {
    float inv = 1.f / (lw + 1e-16f);
    int c0 = l32 * 8;                                // lane owns one full GN group of 8
    float v[8], mu = 0.f;
#pragma unroll
    for (int i = 0; i < 8; ++i) { v[i] = r8[i] * inv + gbias[c0 + i]; mu += v[i]; }
    mu *= 0.125f;
    float q = 0.f;
#pragma unroll
    for (int i = 0; i < 8; ++i) { float d = v[i] - mu; q += d * d; }
    float rs = rsqrtf(q * 0.125f + 1e-5f);
    union { uint4 u; __hip_bfloat16 b[8]; } st;
#pragma unroll
    for (int i = 0; i < 8; ++i) {
      float r = (v[i] - mu) * rs * gnw[c0 + i] + gnb[c0 + i];
      r = (r > 0.f) ? r : (__expf(r) - 1.f);
      st.b[i] = f2b(r);
    }
    *(uint4*)(outp + (size_t)n * 256 + c0) = st.u;
  }
}

// ---------------- launch ----------------
extern "C" void kernel_launch(void* const* d_in, const int* in_sizes, int n_in,
                              void* d_out, int out_size, void* d_ws, size_t ws_size,
                              hipStream_t stream) {
  const float* x      = (const float*)d_in[0];
  const int*   ei     = (const int*)d_in[1];
  const float* pre_w  = (const float*)d_in[2];
  const float* pre_b  = (const float*)d_in[3];
  const float* lin1_b = (const float*)d_in[5];
  const float* n1_w   = (const float*)d_in[6];
  const float* n1_b   = (const float*)d_in[7];
  const float* g1_as  = (const float*)d_in[9];
  const float* g1_ad  = (const float*)d_in[10];
  const float* g1_b   = (const float*)d_in[11];
  const float* n2_w   = (const float*)d_in[12];
  const float* n2_b   = (const float*)d_in[13];
  const float* g2_as  = (const float*)d_in[15];
  const float* g2_ad  = (const float*)d_in[16];
  const float* g2_b   = (const float*)d_in[17];
  const float* n3_w   = (const float*)d_in[18];
  const float* n3_b   = (const float*)d_in[19];
  const float* lin2_b = (const float*)d_in[21];
  const float* skip_b = (const float*)d_in[23];
  float* out = (float*)d_out;

  const int C_IN  = in_sizes[2];          // 256
  const int NN    = in_sizes[0] / C_IN;   // 40000
  const int E     = in_sizes[1] / 2;      // 640000
  const int ET    = E + NN;
  const int C_OUT = in_sizes[21];         // 512
  const int NP    = (NN + 127) & ~127;    // 40064

  __hip_bfloat16* D0 = (__hip_bfloat16*)d_out;        // bf16 scratch in d_out
  __hip_bfloat16* D1 = D0 + (size_t)NP * 256;

  char* basep = (char*)d_ws;
  size_t o = 0;
  auto alloc = [&](size_t bytes) { size_t r = o; o += (bytes + 255) & ~(size_t)255; return r; };
  __hip_bfloat16* Y      = (__hip_bfloat16*)(basep + alloc((size_t)NP * 256 * 2));
  __hip_bfloat16* Wcat   = (__hip_bfloat16*)(basep + alloc((size_t)458752 * 2));
  float*          asrc   = (float*)(basep + alloc((size_t)NP * 4));
  float*          adst   = (float*)(basep + alloc((size_t)NP * 4));
  int*            indptr = (int*)(basep + alloc((size_t)(NN + 1) * 4));
  int*            counts = (int*)(basep + alloc((size_t)NN * 4));
  int*            fill   = (int*)(basep + alloc((size_t)NN * 4));
  int*            bsums  = (int*)(basep + alloc(256));
  int*            csr    = (int*)(basep + alloc((size_t)ET * 4));
  size_t base_need = o;
  size_t xb_need = ((size_t)NP * 256 * 2 + 255) & ~(size_t)255;
  const bool use_xb = (ws_size >= base_need + xb_need);
  __hip_bfloat16* xb = use_xb ? (__hip_bfloat16*)(basep + alloc(xb_need)) : nullptr;

  __hip_bfloat16* Wlin1 = Wcat;
  __hip_bfloat16* Wg1   = Wcat + 65536;
  __hip_bfloat16* Wg2   = Wcat + 131072;
  __hip_bfloat16* Wlin2 = Wcat + 196608;
  __hip_bfloat16* Wskip = Wcat + 327680;

  dim3 blk(256);
  const int nb = (NN + 1023) / 1024;      // 40

  conv_w_k<<<(458752 / 4 + 255) / 256, blk, 0, stream>>>(
      (const float*)d_in[4], (const float*)d_in[8], (const float*)d_in[14],
      (const float*)d_in[20], (const float*)d_in[22], Wcat);
  zero_k<<<(NN + 255) / 256, blk, 0, stream>>>(counts, NN);
  count_deg_k<<<(ET + 255) / 256, blk, 0, stream>>>(ei, E, NN, counts);
  scan_blk_k<<<nb, 1024, 0, stream>>>(counts, indptr, bsums, NN);
  scan_top_k<<<1, 64, 0, stream>>>(bsums, nb);
  scan_add_k<<<nb, 1024, 0, stream>>>(indptr, fill, bsums, NN, ET);
  fill_csr_k<<<(ET + 255) / 256, blk, 0, stream>>>(ei, E, NN, fill, csr, ET);

  gn_elu_k<<<(NN * 32 + 255) / 256, blk, 0, stream>>>(x, pre_w, pre_b, D0, xb, NN * 32);
  // lin1 + GN1 + ELU
  gemm_t<0><<<dim3(1, NP / 64), blk, 0, stream>>>(D0, nullptr, nullptr, Wlin1, nullptr,
      lin1_b, nullptr, n1_w, n1_b, nullptr, nullptr, Y, nullptr, nullptr, nullptr, 256, NN);
  // GAT1
  gemm_t<1><<<dim3(1, NP / 64), blk, 0, stream>>>(Y, nullptr, nullptr, Wg1, nullptr,
      nullptr, nullptr, nullptr, nullptr, g1_as, g1_ad, D0, nullptr, asrc, adst, 256, NN);
  gat_agg_gn_k<<<NN / 4, blk, 0, stream>>>(D0, asrc, adst, indptr, csr, g1_b, n2_w, n2_b, D1, NN, ET);
  // GAT2
  gemm_t<1><<<dim3(1, NP / 64), blk, 0, stream>>>(D1, nullptr, nullptr, Wg2, nullptr,
      nullptr, nullptr, nullptr, nullptr, g2_as, g2_ad, D0, nullptr, asrc, adst, 256, NN);
  gat_agg_gn_k<<<NN / 4, blk, 0, stream>>>(D0, asrc, adst, indptr, csr, g2_b, n3_w, n3_b, Y, NN, ET);
  // lin2 + skip fused -> out (K=512)
  if (use_xb) {
    gemm_t<2><<<dim3(C_OUT / 256, NP / 64), blk, 0, stream>>>(Y, xb, nullptr, Wlin2, Wskip,
        lin2_b, skip_b, nullptr, nullptr, nullptr, nullptr, nullptr, out, nullptr, nullptr, C_OUT, NN);
  } else {
    gemm_t<3><<<dim3(C_OUT / 256, NP / 64), blk, 0, stream>>>(Y, nullptr, x, Wlin2, Wskip,
        lin2_b, skip_b, nullptr, nullptr, nullptr, nullptr, nullptr, out, nullptr, nullptr, C_OUT, NN);
  }
}